// Round 13
// baseline (186.910 us; speedup 1.0000x reference)
//
#include <hip/hip_runtime.h>

typedef unsigned short u16;
typedef unsigned int u32;
typedef __bf16 bf16x8 __attribute__((ext_vector_type(8)));
typedef float f32x4 __attribute__((ext_vector_type(4)));

#define MTOT 8192
#define DM 1024
#define DI 256
#define TT 2048

#define AS1 __attribute__((address_space(1)))
#define AS3 __attribute__((address_space(3)))

__device__ __forceinline__ u16 f2bf(float f) {
    u32 u = __float_as_uint(f);
    return (u16)((u + 0x7fffu + ((u >> 16) & 1u)) >> 16);
}
__device__ __forceinline__ float b2f(u16 b) {
    return __uint_as_float((u32)b << 16);
}

// XCD-chunked bijective swizzle (all swizzled grids are %8==0).
__device__ __forceinline__ int xcd_swizzle(int bid, int nb) {
    return (bid & 7) * (nb >> 3) + (bid >> 3);
}

// ============ prep: X cvt + wv cvt + 5 weight transposes in ONE launch ============
__device__ __forceinline__ void transpose_tile(const float* __restrict__ in,
                                               u16* __restrict__ out, int K, int N,
                                               int bx, int by) {
    __shared__ float t[32][33];
    int n0 = bx * 32, k0 = by * 32;
    int tx = threadIdx.x & 31, ty = threadIdx.x >> 5;
    #pragma unroll
    for (int i = ty; i < 32; i += 8) t[i][tx] = in[(long)(k0 + i) * N + n0 + tx];
    __syncthreads();
    #pragma unroll
    for (int i = ty; i < 32; i += 8) out[(long)(n0 + i) * K + k0 + tx] = f2bf(t[tx][i]);
}

__device__ __forceinline__ void cvt_range(const float* __restrict__ in,
                                          u16* __restrict__ out, long n4, int b, int nb) {
    long i = (long)b * 256 + threadIdx.x;
    long stride = (long)nb * 256;
    for (; i < n4; i += stride) {
        float4 v = reinterpret_cast<const float4*>(in)[i];
        union { u16 u[4]; uint2 p; } o;
        o.u[0] = f2bf(v.x); o.u[1] = f2bf(v.y); o.u[2] = f2bf(v.z); o.u[3] = f2bf(v.w);
        reinterpret_cast<uint2*>(out)[i] = o.p;
    }
}

__global__ __launch_bounds__(256) void prep_kernel(
    const float* __restrict__ x, u16* __restrict__ Xb,
    const float* __restrict__ wq, const float* __restrict__ wk, u16* __restrict__ Wqk_t,
    const float* __restrict__ wv, u16* __restrict__ Wv_b,
    const float* __restrict__ wo, u16* __restrict__ Wo_t,
    const float* __restrict__ w1, u16* __restrict__ W1_t,
    const float* __restrict__ w2, u16* __restrict__ W2_t)
{
    int b = blockIdx.x;
    if (b < 1024) { cvt_range(x, Xb, (long)MTOT * DM / 4, b, 1024); return; }
    b -= 1024;
    if (b < 256)  { transpose_tile(wq, Wqk_t,              1024,  256, b & 7,  b >> 3); return; }
    b -= 256;
    if (b < 256)  { transpose_tile(wk, Wqk_t + 256 * 1024, 1024,  256, b & 7,  b >> 3); return; }
    b -= 256;
    if (b < 256)  { cvt_range(wv, Wv_b, (long)DM * DM / 4, b, 256); return; }
    b -= 256;
    if (b < 1024) { transpose_tile(wo, Wo_t,               1024, 1024, b & 31, b >> 5); return; }
    b -= 1024;
    if (b < 256)  { transpose_tile(w1, W1_t,               1024,  256, b & 7,  b >> 3); return; }
    b -= 256;
    transpose_tile(w2, W2_t, 256, 1024, b & 31, b >> 5);
}

// ------- softmax2: E holds e = exp(s) bf16 (unnormalized). Per row: sum e (fp32),
// write attn_f = e*inv (fp32 output, NONTEMPORAL: never re-read) and inv_sum[row]. -------
__global__ __launch_bounds__(256) void softmax2_kernel(const u16* __restrict__ E,
                                                       float* __restrict__ attn,
                                                       float* __restrict__ inv_sum) {
    long row = blockIdx.x;
    int tid = threadIdx.x;
    uint4 q = reinterpret_cast<const uint4*>(E + row * (long)TT)[tid];
    u32 w4[4] = {q.x, q.y, q.z, q.w};
    float vv[8];
    #pragma unroll
    for (int j = 0; j < 4; ++j) {
        vv[2 * j]     = __uint_as_float(w4[j] << 16);
        vv[2 * j + 1] = __uint_as_float(w4[j] & 0xffff0000u);
    }
    float s = 0.f;
    #pragma unroll
    for (int j = 0; j < 8; ++j) s += vv[j];
    #pragma unroll
    for (int off = 32; off; off >>= 1) s += __shfl_xor(s, off);
    __shared__ float reds[4];
    if ((tid & 63) == 0) reds[tid >> 6] = s;
    __syncthreads();
    s = reds[0] + reds[1] + reds[2] + reds[3];
    float inv = 1.0f / s;
    float* p = attn + row * (long)TT;
    f32x4 o0 = {vv[0] * inv, vv[1] * inv, vv[2] * inv, vv[3] * inv};
    f32x4 o1 = {vv[4] * inv, vv[5] * inv, vv[6] * inv, vv[7] * inv};
    __builtin_nontemporal_store(o0, reinterpret_cast<f32x4*>(p) + tid * 2);
    __builtin_nontemporal_store(o1, reinterpret_cast<f32x4*>(p) + tid * 2 + 1);
    if (tid == 0) inv_sum[row] = inv;
}

// ================== m97-structure 128x128 GEMM (Wvo + FFN) ==================
// MODE: 0 = bf16 C   3 = bf16 relu(C+bias)   7 = fp32(C+bias+addend_b), NT stores
template<int MODE>
__global__ __launch_bounds__(256) void gemm_bt(
    const u16* __restrict__ A, long sA, int lda,
    const u16* __restrict__ Bt, long sB, int ldb,
    u16* __restrict__ Cb, long sCb, int ldcb,
    float* __restrict__ Cf, long sCf, int ldcf,
    int K, float scale,
    const float* __restrict__ bias,
    const u16* __restrict__ addend_b, long sAdd, int ld_add,
    int gx, int gy)
{
    __shared__ __attribute__((aligned(16))) u16 As[128 * 64];
    __shared__ __attribute__((aligned(16))) u16 Bs[128 * 64];

    int lid = xcd_swizzle(blockIdx.x, gridDim.x);
    int x = lid % gx;
    int t = lid / gx;
    int y = t % gy;
    int z = t / gy;
    long tile_m = (long)y * 128, tile_n = (long)x * 128;
    const u16* Az = A + (long)z * sA;
    const u16* Btz = Bt + (long)z * sB;

    const int tid = threadIdx.x;
    const int w = tid >> 6;
    const int l = tid & 63;
    const int lane15 = l & 15;
    const int lhi = l >> 4;

    const int srow = w * 8 + (l >> 3);
    const int scol = (((l & 7) ^ (l >> 3)) << 4) >> 1;

    const u16* aptr = Az + (tile_m + srow) * (long)lda + scol;
    const u16* bptr = Btz + (tile_n + srow) * (long)ldb + scol;

    f32x4 acc[4][4] = {};

    const int wr = (w >> 1) * 64;
    const int wc = (w & 1) * 64;

    for (int k0 = 0; k0 < K; k0 += 64) {
        #pragma unroll
        for (int i = 0; i < 4; ++i) {
            __builtin_amdgcn_global_load_lds(
                (const AS1 void*)(aptr + (long)i * 32 * lda + k0),
                (AS3 void*)((char*)As + i * 4096 + w * 1024), 16, 0, 0);
        }
        #pragma unroll
        for (int i = 0; i < 4; ++i) {
            __builtin_amdgcn_global_load_lds(
                (const AS1 void*)(bptr + (long)i * 32 * ldb + k0),
                (AS3 void*)((char*)Bs + i * 4096 + w * 1024), 16, 0, 0);
        }
        __syncthreads();
        #pragma unroll
        for (int kk = 0; kk < 2; ++kk) {
            bf16x8 af[4], bfr[4];
            const int kb = (kk * 32 + lhi * 8) * 2;
            #pragma unroll
            for (int m = 0; m < 4; ++m) {
                int r = wr + m * 16 + lane15;
                af[m] = *reinterpret_cast<const bf16x8*>(
                    (const char*)As + r * 128 + (kb ^ ((r & 7) << 4)));
            }
            #pragma unroll
            for (int n = 0; n < 4; ++n) {
                int r = wc + n * 16 + lane15;
                bfr[n] = *reinterpret_cast<const bf16x8*>(
                    (const char*)Bs + r * 128 + (kb ^ ((r & 7) << 4)));
            }
            #pragma unroll
            for (int m = 0; m < 4; ++m)
                #pragma unroll
                for (int n = 0; n < 4; ++n)
                    acc[m][n] = __builtin_amdgcn_mfma_f32_16x16x32_bf16(
                        af[m], bfr[n], acc[m][n], 0, 0, 0);
        }
        __syncthreads();
    }

    float* Cfz = Cf + (long)z * sCf;
    u16* Cbz = Cb + (long)z * sCb;
    const u16* addz = addend_b ? addend_b + (long)z * sAdd : addend_b;
    #pragma unroll
    for (int m = 0; m < 4; ++m) {
        #pragma unroll
        for (int n = 0; n < 4; ++n) {
            long grow0 = tile_m + wr + m * 16 + lhi * 4;
            long gcol  = tile_n + wc + n * 16 + lane15;
            #pragma unroll
            for (int r = 0; r < 4; ++r) {
                long grow = grow0 + r;
                float v = acc[m][n][r];
                if (MODE == 3 || MODE == 7) v += bias[gcol];
                if (MODE == 7) v += b2f(addz[grow * (long)ld_add + gcol]);
                if (MODE == 3) v = fmaxf(v, 0.0f);
                if (MODE == 0 || MODE == 3) Cbz[grow * (long)ldcb + gcol] = f2bf(v);
                if (MODE == 7)
                    __builtin_nontemporal_store(v, Cfz + grow * (long)ldcf + gcol);
            }
        }
    }
}

// ====== g2 v4: BM=256, BN=(256|128), BK=64, 8 waves, dedup'd ds_reads, NBUF buffers ======
// BN=256: waves 2M x 4N, wave tile 128x64, MF=8 (reads/MFMA = 0.375).
// BN=128: waves 4M x 2N, wave tile 64x64,  MF=4 (reads/MFMA = 0.5).
// NBUF=2: STAGE(t+1) at top of tile t, end-of-tile vmcnt(0) (covered by the tile).
// NBUF=3 (BN=128 only): STAGE(t+2) at top of tile t, end-of-tile vmcnt(6) keeps
// t+2's loads in flight -> STAGE(t+1) gets ~2 tiles of cover (T4).
// Raw s_barrier only. XOR-16B swizzle on staging source + ds_read (0 conflicts).
// MODE: 0 = bf16(C*scale)        8 = bf16(exp(C*scale))
//       9 = bf16(C*inv_sum[row] + bias[col] + bf16 addend)
template<int BN, int MODE, int NBUF>
__device__ __forceinline__ void g2_body(
    char* ldsb,
    const u16* __restrict__ A, int lda,
    const u16* __restrict__ Bt, int ldb,
    u16* __restrict__ Cb, int ldcb,
    int K, float scale,
    const float* __restrict__ bias,
    const u16* __restrict__ addend_b, int ld_add,
    const float* __restrict__ inv_sum,
    long tile_m, long tile_n)
{
    constexpr int WNM = (BN == 256) ? 2 : 4;   // waves along M
    constexpr int WNN = 8 / WNM;               // waves along N
    constexpr int MF  = 16 / WNM;              // m-frags per wave (8 or 4)
    constexpr int WTM = 256 / WNM;             // wave tile rows (128 or 64)
    constexpr int BUFB = (256 + BN) * 128;     // bytes per K-tile buffer
    constexpr int AC = 4;                      // A stage chunks (64 rows each)
    constexpr int BC = BN / 64;                // B stage chunks

    const int tid = threadIdx.x;
    const int w = tid >> 6, l = tid & 63;
    const int lane15 = l & 15, lhi = l >> 4;
    const int sw = (l & 7) << 4;
    const int wm = w / WNN, wn = w % WNN;

    const int srow = w * 8 + (l >> 3);
    const int scol = ((l & 7) ^ (l >> 3)) * 8;
    const u16* aS = A + (tile_m + srow) * (long)lda + scol;
    const u16* bS = Bt + (tile_n + srow) * (long)ldb + scol;

    auto STAGE = [&](int t) {
        const long kof = (long)t << 6;
        char* buf = ldsb + (size_t)(t % NBUF) * BUFB;
        #pragma unroll
        for (int c = 0; c < AC; ++c)
            __builtin_amdgcn_global_load_lds(
                (const AS1 void*)(aS + (long)(c * 64) * lda + kof),
                (AS3 void*)(buf + c * 8192 + w * 1024), 16, 0, 0);
        #pragma unroll
        for (int c = 0; c < BC; ++c)
            __builtin_amdgcn_global_load_lds(
                (const AS1 void*)(bS + (long)(c * 64) * ldb + kof),
                (AS3 void*)(buf + 32768 + c * 8192 + w * 1024), 16, 0, 0);
    };

    f32x4 acc[MF][4] = {};
    const int NT = K >> 6;

    if (NBUF == 3) {
        STAGE(0); STAGE(1);
        asm volatile("s_waitcnt vmcnt(6)" ::: "memory");   // AC+BC=6 (BN=128): tile1 in flight
    } else {
        STAGE(0);
        asm volatile("s_waitcnt vmcnt(0)" ::: "memory");
    }
    __builtin_amdgcn_s_barrier();

    for (int t = 0; t < NT; ++t) {
        const char* ab = ldsb + (size_t)(t % NBUF) * BUFB;
        const char* bb = ab + 32768;
        const bool more = (t + 1) < NT;
        const bool st2 = (t + 2) < NT;

        if (NBUF == 3) { if (st2) STAGE(t + 2); }
        else           { if (more) STAGE(t + 1); }

        // B fragments: read once per K-tile
        bf16x8 bfr[4][2];
        #pragma unroll
        for (int n = 0; n < 4; ++n) {
            const int rb = wn * 64 + n * 16 + lane15;
            #pragma unroll
            for (int ks = 0; ks < 2; ++ks)
                bfr[n][ks] = *reinterpret_cast<const bf16x8*>(
                    bb + rb * 128 + ((ks * 64 + lhi * 16) ^ sw));
        }
        // A in halves of 4 m-frags; each half: 8 reads -> 32 MFMA
        #pragma unroll
        for (int h = 0; h < MF / 4; ++h) {
            bf16x8 af[4][2];
            #pragma unroll
            for (int m = 0; m < 4; ++m) {
                const int r = wm * WTM + h * 64 + m * 16 + lane15;
                #pragma unroll
                for (int ks = 0; ks < 2; ++ks)
                    af[m][ks] = *reinterpret_cast<const bf16x8*>(
                        ab + r * 128 + ((ks * 64 + lhi * 16) ^ sw));
            }
            __builtin_amdgcn_s_barrier();
            __builtin_amdgcn_s_setprio(1);
            #pragma unroll
            for (int m = 0; m < 4; ++m)
                #pragma unroll
                for (int n = 0; n < 4; ++n)
                    #pragma unroll
                    for (int ks = 0; ks < 2; ++ks)
                        acc[h * 4 + m][n] = __builtin_amdgcn_mfma_f32_16x16x32_bf16(
                            af[m][ks], bfr[n][ks], acc[h * 4 + m][n], 0, 0, 0);
            __builtin_amdgcn_s_setprio(0);
        }
        if (NBUF == 3) {
            if (more) {
                if (st2) asm volatile("s_waitcnt vmcnt(6)" ::: "memory");
                else     asm volatile("s_waitcnt vmcnt(0)" ::: "memory");
            }
        } else {
            if (more) asm volatile("s_waitcnt vmcnt(0)" ::: "memory");
        }
        __builtin_amdgcn_s_barrier();
    }

    #pragma unroll
    for (int mf = 0; mf < MF; ++mf) {
        #pragma unroll
        for (int nf = 0; nf < 4; ++nf) {
            const long grow0 = tile_m + wm * WTM + mf * 16 + lhi * 4;
            const long gcol  = tile_n + wn * 64 + nf * 16 + lane15;
            #pragma unroll
            for (int r = 0; r < 4; ++r) {
                const long grow = grow0 + r;
                float v = acc[mf][nf][r];
                if (MODE == 0) v *= scale;
                if (MODE == 8) v = __expf(v * scale);
                if (MODE == 9) v = v * inv_sum[grow] + bias[gcol]
                                   + b2f(addend_b[grow * (long)ld_add + gcol]);
                Cb[grow * (long)ldcb + gcol] = f2bf(v);
            }
        }
    }
}

template<int BN, int MODE, int NBUF>
__global__ __launch_bounds__(512) void g2k(
    const u16* __restrict__ A, long sA, int lda,
    const u16* __restrict__ Bt, long sB, int ldb,
    u16* __restrict__ Cb, long sCb, int ldcb,
    int K, float scale,
    const float* __restrict__ bias,
    const u16* __restrict__ addend_b, long sAdd, int ld_add,
    const float* __restrict__ inv_sum, long sInv,
    int gx, int tpz)
{
    __shared__ __attribute__((aligned(16))) char lds[(256 + BN) * 128 * NBUF];
    int lid = xcd_swizzle(blockIdx.x, gridDim.x);
    int z = lid / tpz, rem = lid % tpz;
    int x = rem % gx, y = rem / gx;
    g2_body<BN, MODE, NBUF>(lds,
                      A + (long)z * sA, lda, Bt + (long)z * sB, ldb,
                      Cb + (long)z * sCb, ldcb, K, scale, bias,
                      addend_b ? addend_b + (long)z * sAdd : addend_b, ld_add,
                      inv_sum ? inv_sum + (long)z * sInv : inv_sum,
                      (long)y * 256, (long)x * BN);
}

// Merged QK + VW^T dispatch, 256 blocks = FULL CU fill (K=1024 both):
// lids [0,128):   QK = Xb @ Wqk_t^T (8192x512): BN=128, NBUF=3, x = lid&3, y = lid>>2
// lids [128,256): VW^T = Wvo_t @ Xb^T -> VWt (1024,8192): BN=256, NBUF=2, y-fast
//   (y = l2&3, x = l2>>2): per-XCD = full Wvo_t (2MB) + 4 X panels (2MB) ~= L2.
__global__ __launch_bounds__(512) void g2_qkvw(
    const u16* __restrict__ Xb, const u16* __restrict__ Wqk_t, u16* __restrict__ QKb,
    const u16* __restrict__ Wvo_t, u16* __restrict__ VWt)
{
    __shared__ __attribute__((aligned(16))) char lds[147456];
    int lid = xcd_swizzle(blockIdx.x, gridDim.x);
    if (lid < 128) {
        int x = lid & 3, y = lid >> 2;
        g2_body<128, 0, 3>(lds, Xb, 1024, Wqk_t, 1024, QKb, 512,
                        1024, 1.0f, (const float*)nullptr, (const u16*)nullptr, 0,
                        (const float*)nullptr, (long)y * 256, (long)x * 128);
    } else {
        int l2 = lid - 128;
        int y = l2 & 3, x = l2 >> 2;
        g2_body<256, 0, 2>(lds, Wvo_t, 1024, Xb, 1024, VWt, 8192,
                        1024, 1.0f, (const float*)nullptr, (const u16*)nullptr, 0,
                        (const float*)nullptr, (long)y * 256, (long)x * 256);
    }
}

extern "C" void kernel_launch(void* const* d_in, const int* in_sizes, int n_in,
                              void* d_out, int out_size, void* d_ws, size_t ws_size,
                              hipStream_t stream)
{
    const float* x  = (const float*)d_in[0];
    const float* wq = (const float*)d_in[1];
    const float* wk = (const float*)d_in[2];
    const float* wv = (const float*)d_in[3];
    const float* wo = (const float*)d_in[4];
    const float* bo = (const float*)d_in[5];
    const float* w1 = (const float*)d_in[6];
    const float* b1 = (const float*)d_in[7];
    const float* w2 = (const float*)d_in[8];
    const float* b2 = (const float*)d_in[9];

    float* out_f  = (float*)d_out;
    float* attn_f = out_f + (long)MTOT * DM;

    char* ws = (char*)d_ws;
    u16* Xb    = (u16*)(ws + 0);            // 16 MB bf16 X (also residual addend)
    u16* Wqk_t = (u16*)(ws + 16777216);     // 1 MB  (512,1024)
    u16* Wv_b  = (u16*)(ws + 17825792);     // 2 MB  wv bf16 (as-is, K-contig)
    u16* Wo_t  = (u16*)(ws + 19922944);     // 2 MB  wo^T
    u16* W1_t  = (u16*)(ws + 22020096);     // 0.5 MB
    u16* W2_t  = (u16*)(ws + 22544384);     // 0.5 MB
    u16* Wvo_t = (u16*)(ws + 23068672);     // 2 MB  (Wv@Wo)^T
    u16* QKb   = (u16*)(ws + 25165824);     // 8 MB  (8192,512) (reused as h)
    u16* VWt   = (u16*)(ws + 33554432);     // 16 MB (1024,8192)
    u16* attnb = (u16*)(ws + 50331648);     // 32 MB e = exp(scores) bf16 (unnormalized)
    u16* res_b = (u16*)(ws + 83886080);     // 16 MB residual bf16
    float* inv_sum = (float*)(ws + 100663296); // 32 KB per-row 1/sum
    u16* hb    = QKb;

    dim3 blk(256), blk5(512);

    // 1. prep: X cvt, wv cvt, wq/wk/wo/w1/w2 transposes
    prep_kernel<<<dim3(3328), blk, 0, stream>>>(x, Xb, wq, wk, Wqk_t, wv, Wv_b,
                                                wo, Wo_t, w1, W1_t, w2, W2_t);
    // 2. Wvo^T = Wo_t @ Wv_b^T (m97 mode 0, coalesced stores)
    gemm_bt<0><<<dim3(64), blk, 0, stream>>>(
        Wo_t, 0L, 1024, Wv_b, 0L, 1024, Wvo_t, 0L, 1024,
        (float*)nullptr, 0L, 0, 1024, 1.0f, (const float*)nullptr,
        (const u16*)nullptr, 0L, 0, 8, 8);
    // 3. merged QK (BN=128 NBUF=3) + VW^T (BN=256, swapped operands) — 256 blocks
    g2_qkvw<<<dim3(256), blk5, 0, stream>>>(Xb, Wqk_t, QKb, Wvo_t, VWt);
    // 4. e = exp(Q @ K^T / 16) bf16 (g2 v4 BN=256 MODE 8, 256 blocks, per batch)
    g2k<256, 8, 2><<<dim3(256), blk5, 0, stream>>>(
        QKb, (long)2048 * 512, 512, QKb + 256, (long)2048 * 512, 512,
        attnb, (long)2048 * 2048, 2048,
        256, 0.0625f, (const float*)nullptr, (const u16*)nullptr, 0L, 0,
        (const float*)nullptr, 0L, 8, 64);
    // 5. softmax2: row sums of e -> attn_f (fp32 output, NT stores) + inv_sum
    softmax2_kernel<<<dim3(8192), blk, 0, stream>>>(attnb, attn_f, inv_sum);
    // 6. residual(bf16) = bf16((e @ VW)*inv_sum + bo + Xb)
    //    (g2 v4 BN=128 MODE 9, 3-buffer counted pipeline, 256 blocks)
    g2k<128, 9, 3><<<dim3(256), blk5, 0, stream>>>(
        attnb, (long)2048 * 2048, 2048, VWt, 2048L, 8192,
        res_b, (long)2048 * 1024, 1024,
        2048, 1.0f, bo, Xb, (long)2048 * 1024, 1024,
        inv_sum, 2048L, 8, 64);
    // 7. h = relu(residual @ w1 + b1) (m97)
    gemm_bt<3><<<dim3(128), blk, 0, stream>>>(
        res_b, 0L, 1024, W1_t, 0L, 1024, hb, 0L, 256,
        (float*)nullptr, 0L, 0, 1024, 1.0f, b1, (const u16*)nullptr, 0L, 0, 2, 64);
    // 8. out = residual + h @ w2 + b2 (m97, fp32 NT stores)
    gemm_bt<7><<<dim3(512), blk, 0, stream>>>(
        hb, 0L, 256, W2_t, 0L, 256, (u16*)nullptr, 0L, 0,
        out_f, 0L, 1024, 256, 1.0f, b2, res_b, 0L, 1024, 8, 64);
}

// Round 14
// 185.342 us; speedup vs baseline: 1.0085x; 1.0085x over previous
//
#include <hip/hip_runtime.h>

typedef unsigned short u16;
typedef unsigned int u32;
typedef __bf16 bf16x8 __attribute__((ext_vector_type(8)));
typedef float f32x4 __attribute__((ext_vector_type(4)));

#define MTOT 8192
#define DM 1024
#define DI 256
#define TT 2048

#define AS1 __attribute__((address_space(1)))
#define AS3 __attribute__((address_space(3)))

__device__ __forceinline__ u16 f2bf(float f) {
    u32 u = __float_as_uint(f);
    return (u16)((u + 0x7fffu + ((u >> 16) & 1u)) >> 16);
}
__device__ __forceinline__ float b2f(u16 b) {
    return __uint_as_float((u32)b << 16);
}

// XCD-chunked bijective swizzle (all swizzled grids are %8==0).
__device__ __forceinline__ int xcd_swizzle(int bid, int nb) {
    return (bid & 7) * (nb >> 3) + (bid >> 3);
}

// ============ prep: X cvt + wv cvt + 5 weight transposes in ONE launch ============
__device__ __forceinline__ void transpose_tile(const float* __restrict__ in,
                                               u16* __restrict__ out, int K, int N,
                                               int bx, int by) {
    __shared__ float t[32][33];
    int n0 = bx * 32, k0 = by * 32;
    int tx = threadIdx.x & 31, ty = threadIdx.x >> 5;
    #pragma unroll
    for (int i = ty; i < 32; i += 8) t[i][tx] = in[(long)(k0 + i) * N + n0 + tx];
    __syncthreads();
    #pragma unroll
    for (int i = ty; i < 32; i += 8) out[(long)(n0 + i) * K + k0 + tx] = f2bf(t[tx][i]);
}

__device__ __forceinline__ void cvt_range(const float* __restrict__ in,
                                          u16* __restrict__ out, long n4, int b, int nb) {
    long i = (long)b * 256 + threadIdx.x;
    long stride = (long)nb * 256;
    for (; i < n4; i += stride) {
        float4 v = reinterpret_cast<const float4*>(in)[i];
        union { u16 u[4]; uint2 p; } o;
        o.u[0] = f2bf(v.x); o.u[1] = f2bf(v.y); o.u[2] = f2bf(v.z); o.u[3] = f2bf(v.w);
        reinterpret_cast<uint2*>(out)[i] = o.p;
    }
}

__global__ __launch_bounds__(256) void prep_kernel(
    const float* __restrict__ x, u16* __restrict__ Xb,
    const float* __restrict__ wq, const float* __restrict__ wk, u16* __restrict__ Wqk_t,
    const float* __restrict__ wv, u16* __restrict__ Wv_b,
    const float* __restrict__ wo, u16* __restrict__ Wo_t,
    const float* __restrict__ w1, u16* __restrict__ W1_t,
    const float* __restrict__ w2, u16* __restrict__ W2_t)
{
    int b = blockIdx.x;
    if (b < 1024) { cvt_range(x, Xb, (long)MTOT * DM / 4, b, 1024); return; }
    b -= 1024;
    if (b < 256)  { transpose_tile(wq, Wqk_t,              1024,  256, b & 7,  b >> 3); return; }
    b -= 256;
    if (b < 256)  { transpose_tile(wk, Wqk_t + 256 * 1024, 1024,  256, b & 7,  b >> 3); return; }
    b -= 256;
    if (b < 256)  { cvt_range(wv, Wv_b, (long)DM * DM / 4, b, 256); return; }
    b -= 256;
    if (b < 1024) { transpose_tile(wo, Wo_t,               1024, 1024, b & 31, b >> 5); return; }
    b -= 1024;
    if (b < 256)  { transpose_tile(w1, W1_t,               1024,  256, b & 7,  b >> 3); return; }
    b -= 256;
    transpose_tile(w2, W2_t, 256, 1024, b & 31, b >> 5);
}

// ------- softmax2: E holds e = exp(s) bf16 (unnormalized). Per row: sum e (fp32),
// write attn_f = e*inv (fp32 output, NONTEMPORAL: never re-read) and inv_sum[row]. -------
__global__ __launch_bounds__(256) void softmax2_kernel(const u16* __restrict__ E,
                                                       float* __restrict__ attn,
                                                       float* __restrict__ inv_sum) {
    long row = blockIdx.x;
    int tid = threadIdx.x;
    uint4 q = reinterpret_cast<const uint4*>(E + row * (long)TT)[tid];
    u32 w4[4] = {q.x, q.y, q.z, q.w};
    float vv[8];
    #pragma unroll
    for (int j = 0; j < 4; ++j) {
        vv[2 * j]     = __uint_as_float(w4[j] << 16);
        vv[2 * j + 1] = __uint_as_float(w4[j] & 0xffff0000u);
    }
    float s = 0.f;
    #pragma unroll
    for (int j = 0; j < 8; ++j) s += vv[j];
    #pragma unroll
    for (int off = 32; off; off >>= 1) s += __shfl_xor(s, off);
    __shared__ float reds[4];
    if ((tid & 63) == 0) reds[tid >> 6] = s;
    __syncthreads();
    s = reds[0] + reds[1] + reds[2] + reds[3];
    float inv = 1.0f / s;
    float* p = attn + row * (long)TT;
    f32x4 o0 = {vv[0] * inv, vv[1] * inv, vv[2] * inv, vv[3] * inv};
    f32x4 o1 = {vv[4] * inv, vv[5] * inv, vv[6] * inv, vv[7] * inv};
    __builtin_nontemporal_store(o0, reinterpret_cast<f32x4*>(p) + tid * 2);
    __builtin_nontemporal_store(o1, reinterpret_cast<f32x4*>(p) + tid * 2 + 1);
    if (tid == 0) inv_sum[row] = inv;
}

// ================== m97-structure 128x128 GEMM (Wvo + FFN) ==================
// MODE: 0 = bf16 C   3 = bf16 relu(C+bias)   7 = fp32(C+bias+addend_b), NT stores
template<int MODE>
__global__ __launch_bounds__(256) void gemm_bt(
    const u16* __restrict__ A, long sA, int lda,
    const u16* __restrict__ Bt, long sB, int ldb,
    u16* __restrict__ Cb, long sCb, int ldcb,
    float* __restrict__ Cf, long sCf, int ldcf,
    int K, float scale,
    const float* __restrict__ bias,
    const u16* __restrict__ addend_b, long sAdd, int ld_add,
    int gx, int gy)
{
    __shared__ __attribute__((aligned(16))) u16 As[128 * 64];
    __shared__ __attribute__((aligned(16))) u16 Bs[128 * 64];

    int lid = xcd_swizzle(blockIdx.x, gridDim.x);
    int x = lid % gx;
    int t = lid / gx;
    int y = t % gy;
    int z = t / gy;
    long tile_m = (long)y * 128, tile_n = (long)x * 128;
    const u16* Az = A + (long)z * sA;
    const u16* Btz = Bt + (long)z * sB;

    const int tid = threadIdx.x;
    const int w = tid >> 6;
    const int l = tid & 63;
    const int lane15 = l & 15;
    const int lhi = l >> 4;

    const int srow = w * 8 + (l >> 3);
    const int scol = (((l & 7) ^ (l >> 3)) << 4) >> 1;

    const u16* aptr = Az + (tile_m + srow) * (long)lda + scol;
    const u16* bptr = Btz + (tile_n + srow) * (long)ldb + scol;

    f32x4 acc[4][4] = {};

    const int wr = (w >> 1) * 64;
    const int wc = (w & 1) * 64;

    for (int k0 = 0; k0 < K; k0 += 64) {
        #pragma unroll
        for (int i = 0; i < 4; ++i) {
            __builtin_amdgcn_global_load_lds(
                (const AS1 void*)(aptr + (long)i * 32 * lda + k0),
                (AS3 void*)((char*)As + i * 4096 + w * 1024), 16, 0, 0);
        }
        #pragma unroll
        for (int i = 0; i < 4; ++i) {
            __builtin_amdgcn_global_load_lds(
                (const AS1 void*)(bptr + (long)i * 32 * ldb + k0),
                (AS3 void*)((char*)Bs + i * 4096 + w * 1024), 16, 0, 0);
        }
        __syncthreads();
        #pragma unroll
        for (int kk = 0; kk < 2; ++kk) {
            bf16x8 af[4], bfr[4];
            const int kb = (kk * 32 + lhi * 8) * 2;
            #pragma unroll
            for (int m = 0; m < 4; ++m) {
                int r = wr + m * 16 + lane15;
                af[m] = *reinterpret_cast<const bf16x8*>(
                    (const char*)As + r * 128 + (kb ^ ((r & 7) << 4)));
            }
            #pragma unroll
            for (int n = 0; n < 4; ++n) {
                int r = wc + n * 16 + lane15;
                bfr[n] = *reinterpret_cast<const bf16x8*>(
                    (const char*)Bs + r * 128 + (kb ^ ((r & 7) << 4)));
            }
            #pragma unroll
            for (int m = 0; m < 4; ++m)
                #pragma unroll
                for (int n = 0; n < 4; ++n)
                    acc[m][n] = __builtin_amdgcn_mfma_f32_16x16x32_bf16(
                        af[m], bfr[n], acc[m][n], 0, 0, 0);
        }
        __syncthreads();
    }

    float* Cfz = Cf + (long)z * sCf;
    u16* Cbz = Cb + (long)z * sCb;
    const u16* addz = addend_b ? addend_b + (long)z * sAdd : addend_b;
    #pragma unroll
    for (int m = 0; m < 4; ++m) {
        #pragma unroll
        for (int n = 0; n < 4; ++n) {
            long grow0 = tile_m + wr + m * 16 + lhi * 4;
            long gcol  = tile_n + wc + n * 16 + lane15;
            #pragma unroll
            for (int r = 0; r < 4; ++r) {
                long grow = grow0 + r;
                float v = acc[m][n][r];
                if (MODE == 3 || MODE == 7) v += bias[gcol];
                if (MODE == 7) v += b2f(addz[grow * (long)ld_add + gcol]);
                if (MODE == 3) v = fmaxf(v, 0.0f);
                if (MODE == 0 || MODE == 3) Cbz[grow * (long)ldcb + gcol] = f2bf(v);
                if (MODE == 7)
                    __builtin_nontemporal_store(v, Cfz + grow * (long)ldcf + gcol);
            }
        }
    }
}

// ====== g2 v4: BM=256, BN=(256|128), BK=64, 8 waves, dedup'd ds_reads, NBUF buffers ======
// BN=256: waves 2M x 4N, wave tile 128x64, MF=8 (reads/MFMA = 0.375).
// BN=128: waves 4M x 2N, wave tile 64x64,  MF=4 (reads/MFMA = 0.5).
// NBUF=2: STAGE(t+1) at top of tile t, end-of-tile vmcnt(0) (covered by the tile).
// NBUF=3 (BN=128 only): STAGE(t+2) at top of tile t, end-of-tile vmcnt(6) keeps
// t+2's loads in flight -> STAGE(t+1) gets ~2 tiles of cover (T4).
// Raw s_barrier only. XOR-16B swizzle on staging source + ds_read (0 conflicts).
// MODE: 0 = bf16(C*scale)        8 = bf16(exp(C*scale))
//       9 = bf16(C*inv_sum[row] + bias[col] + bf16 addend)
template<int BN, int MODE, int NBUF>
__device__ __forceinline__ void g2_body(
    char* ldsb,
    const u16* __restrict__ A, int lda,
    const u16* __restrict__ Bt, int ldb,
    u16* __restrict__ Cb, int ldcb,
    int K, float scale,
    const float* __restrict__ bias,
    const u16* __restrict__ addend_b, int ld_add,
    const float* __restrict__ inv_sum,
    long tile_m, long tile_n)
{
    constexpr int WNM = (BN == 256) ? 2 : 4;   // waves along M
    constexpr int WNN = 8 / WNM;               // waves along N
    constexpr int MF  = 16 / WNM;              // m-frags per wave (8 or 4)
    constexpr int WTM = 256 / WNM;             // wave tile rows (128 or 64)
    constexpr int BUFB = (256 + BN) * 128;     // bytes per K-tile buffer
    constexpr int AC = 4;                      // A stage chunks (64 rows each)
    constexpr int BC = BN / 64;                // B stage chunks

    const int tid = threadIdx.x;
    const int w = tid >> 6, l = tid & 63;
    const int lane15 = l & 15, lhi = l >> 4;
    const int sw = (l & 7) << 4;
    const int wm = w / WNN, wn = w % WNN;

    const int srow = w * 8 + (l >> 3);
    const int scol = ((l & 7) ^ (l >> 3)) * 8;
    const u16* aS = A + (tile_m + srow) * (long)lda + scol;
    const u16* bS = Bt + (tile_n + srow) * (long)ldb + scol;

    auto STAGE = [&](int t) {
        const long kof = (long)t << 6;
        char* buf = ldsb + (size_t)(t % NBUF) * BUFB;
        #pragma unroll
        for (int c = 0; c < AC; ++c)
            __builtin_amdgcn_global_load_lds(
                (const AS1 void*)(aS + (long)(c * 64) * lda + kof),
                (AS3 void*)(buf + c * 8192 + w * 1024), 16, 0, 0);
        #pragma unroll
        for (int c = 0; c < BC; ++c)
            __builtin_amdgcn_global_load_lds(
                (const AS1 void*)(bS + (long)(c * 64) * ldb + kof),
                (AS3 void*)(buf + 32768 + c * 8192 + w * 1024), 16, 0, 0);
    };

    f32x4 acc[MF][4] = {};
    const int NT = K >> 6;

    if (NBUF == 3) {
        STAGE(0); STAGE(1);
        asm volatile("s_waitcnt vmcnt(6)" ::: "memory");   // AC+BC=6 (BN=128): tile1 in flight
    } else {
        STAGE(0);
        asm volatile("s_waitcnt vmcnt(0)" ::: "memory");
    }
    __builtin_amdgcn_s_barrier();

    for (int t = 0; t < NT; ++t) {
        const char* ab = ldsb + (size_t)(t % NBUF) * BUFB;
        const char* bb = ab + 32768;
        const bool more = (t + 1) < NT;
        const bool st2 = (t + 2) < NT;

        if (NBUF == 3) { if (st2) STAGE(t + 2); }
        else           { if (more) STAGE(t + 1); }

        // B fragments: read once per K-tile
        bf16x8 bfr[4][2];
        #pragma unroll
        for (int n = 0; n < 4; ++n) {
            const int rb = wn * 64 + n * 16 + lane15;
            #pragma unroll
            for (int ks = 0; ks < 2; ++ks)
                bfr[n][ks] = *reinterpret_cast<const bf16x8*>(
                    bb + rb * 128 + ((ks * 64 + lhi * 16) ^ sw));
        }
        // A in halves of 4 m-frags; each half: 8 reads -> 32 MFMA
        #pragma unroll
        for (int h = 0; h < MF / 4; ++h) {
            bf16x8 af[4][2];
            #pragma unroll
            for (int m = 0; m < 4; ++m) {
                const int r = wm * WTM + h * 64 + m * 16 + lane15;
                #pragma unroll
                for (int ks = 0; ks < 2; ++ks)
                    af[m][ks] = *reinterpret_cast<const bf16x8*>(
                        ab + r * 128 + ((ks * 64 + lhi * 16) ^ sw));
            }
            __builtin_amdgcn_s_barrier();
            __builtin_amdgcn_s_setprio(1);
            #pragma unroll
            for (int m = 0; m < 4; ++m)
                #pragma unroll
                for (int n = 0; n < 4; ++n)
                    #pragma unroll
                    for (int ks = 0; ks < 2; ++ks)
                        acc[h * 4 + m][n] = __builtin_amdgcn_mfma_f32_16x16x32_bf16(
                            af[m][ks], bfr[n][ks], acc[h * 4 + m][n], 0, 0, 0);
            __builtin_amdgcn_s_setprio(0);
        }
        if (NBUF == 3) {
            if (more) {
                if (st2) asm volatile("s_waitcnt vmcnt(6)" ::: "memory");
                else     asm volatile("s_waitcnt vmcnt(0)" ::: "memory");
            }
        } else {
            if (more) asm volatile("s_waitcnt vmcnt(0)" ::: "memory");
        }
        __builtin_amdgcn_s_barrier();
    }

    #pragma unroll
    for (int mf = 0; mf < MF; ++mf) {
        #pragma unroll
        for (int nf = 0; nf < 4; ++nf) {
            const long grow0 = tile_m + wm * WTM + mf * 16 + lhi * 4;
            const long gcol  = tile_n + wn * 64 + nf * 16 + lane15;
            #pragma unroll
            for (int r = 0; r < 4; ++r) {
                const long grow = grow0 + r;
                float v = acc[mf][nf][r];
                if (MODE == 0) v *= scale;
                if (MODE == 8) v = __expf(v * scale);
                if (MODE == 9) v = v * inv_sum[grow] + bias[gcol]
                                   + b2f(addend_b[grow * (long)ld_add + gcol]);
                Cb[grow * (long)ldcb + gcol] = f2bf(v);
            }
        }
    }
}

template<int BN, int MODE, int NBUF>
__global__ __launch_bounds__(512) void g2k(
    const u16* __restrict__ A, long sA, int lda,
    const u16* __restrict__ Bt, long sB, int ldb,
    u16* __restrict__ Cb, long sCb, int ldcb,
    int K, float scale,
    const float* __restrict__ bias,
    const u16* __restrict__ addend_b, long sAdd, int ld_add,
    const float* __restrict__ inv_sum, long sInv,
    int gx, int tpz)
{
    __shared__ __attribute__((aligned(16))) char lds[(256 + BN) * 128 * NBUF];
    int lid = xcd_swizzle(blockIdx.x, gridDim.x);
    int z = lid / tpz, rem = lid % tpz;
    int x = rem % gx, y = rem / gx;
    g2_body<BN, MODE, NBUF>(lds,
                      A + (long)z * sA, lda, Bt + (long)z * sB, ldb,
                      Cb + (long)z * sCb, ldcb, K, scale, bias,
                      addend_b ? addend_b + (long)z * sAdd : addend_b, ld_add,
                      inv_sum ? inv_sum + (long)z * sInv : inv_sum,
                      (long)y * 256, (long)x * BN);
}

// Merged QK + VW^T dispatch (K=1024 both) — r11 geometry (best known):
// lids [0,64):   QK = Xb @ Wqk_t^T (8192x512): BN=256, x = lid&1, y = lid>>1
//   (per-XCD: 4 A panels 2MB + full Wqk_t 1MB = 3MB, fits L2)
// lids [64,192): VW^T = Wvo_t @ Xb^T -> VWt (1024,8192) row-major, y-fast
//   (y = l2&3, x = l2>>2): per-XCD = full Wvo_t (2MB) + 4 X panels (2MB) ~= L2.
__global__ __launch_bounds__(512) void g2_qkvw(
    const u16* __restrict__ Xb, const u16* __restrict__ Wqk_t, u16* __restrict__ QKb,
    const u16* __restrict__ Wvo_t, u16* __restrict__ VWt)
{
    __shared__ __attribute__((aligned(16))) char lds[131072];
    int lid = xcd_swizzle(blockIdx.x, gridDim.x);
    if (lid < 64) {
        int x = lid & 1, y = lid >> 1;
        g2_body<256, 0, 2>(lds, Xb, 1024, Wqk_t, 1024, QKb, 512,
                        1024, 1.0f, (const float*)nullptr, (const u16*)nullptr, 0,
                        (const float*)nullptr, (long)y * 256, (long)x * 256);
    } else {
        int l2 = lid - 64;
        int y = l2 & 3, x = l2 >> 2;
        g2_body<256, 0, 2>(lds, Wvo_t, 1024, Xb, 1024, VWt, 8192,
                        1024, 1.0f, (const float*)nullptr, (const u16*)nullptr, 0,
                        (const float*)nullptr, (long)y * 256, (long)x * 256);
    }
}

extern "C" void kernel_launch(void* const* d_in, const int* in_sizes, int n_in,
                              void* d_out, int out_size, void* d_ws, size_t ws_size,
                              hipStream_t stream)
{
    const float* x  = (const float*)d_in[0];
    const float* wq = (const float*)d_in[1];
    const float* wk = (const float*)d_in[2];
    const float* wv = (const float*)d_in[3];
    const float* wo = (const float*)d_in[4];
    const float* bo = (const float*)d_in[5];
    const float* w1 = (const float*)d_in[6];
    const float* b1 = (const float*)d_in[7];
    const float* w2 = (const float*)d_in[8];
    const float* b2 = (const float*)d_in[9];

    float* out_f  = (float*)d_out;
    float* attn_f = out_f + (long)MTOT * DM;

    char* ws = (char*)d_ws;
    u16* Xb    = (u16*)(ws + 0);            // 16 MB bf16 X (also residual addend)
    u16* Wqk_t = (u16*)(ws + 16777216);     // 1 MB  (512,1024)
    u16* Wv_b  = (u16*)(ws + 17825792);     // 2 MB  wv bf16 (as-is, K-contig)
    u16* Wo_t  = (u16*)(ws + 19922944);     // 2 MB  wo^T
    u16* W1_t  = (u16*)(ws + 22020096);     // 0.5 MB
    u16* W2_t  = (u16*)(ws + 22544384);     // 0.5 MB
    u16* Wvo_t = (u16*)(ws + 23068672);     // 2 MB  (Wv@Wo)^T
    u16* QKb   = (u16*)(ws + 25165824);     // 8 MB  (8192,512) (reused as h)
    u16* VWt   = (u16*)(ws + 33554432);     // 16 MB (1024,8192)
    u16* attnb = (u16*)(ws + 50331648);     // 32 MB e = exp(scores) bf16 (unnormalized)
    u16* res_b = (u16*)(ws + 83886080);     // 16 MB residual bf16
    float* inv_sum = (float*)(ws + 100663296); // 32 KB per-row 1/sum
    u16* hb    = QKb;

    dim3 blk(256), blk5(512);

    // 1. prep: X cvt, wv cvt, wq/wk/wo/w1/w2 transposes
    prep_kernel<<<dim3(3328), blk, 0, stream>>>(x, Xb, wq, wk, Wqk_t, wv, Wv_b,
                                                wo, Wo_t, w1, W1_t, w2, W2_t);
    // 2. Wvo^T = Wo_t @ Wv_b^T (m97 mode 0, coalesced stores)
    gemm_bt<0><<<dim3(64), blk, 0, stream>>>(
        Wo_t, 0L, 1024, Wv_b, 0L, 1024, Wvo_t, 0L, 1024,
        (float*)nullptr, 0L, 0, 1024, 1.0f, (const float*)nullptr,
        (const u16*)nullptr, 0L, 0, 8, 8);
    // 3. merged QK + VW^T (g2 v4, 192 blocks, r11 geometry)
    g2_qkvw<<<dim3(192), blk5, 0, stream>>>(Xb, Wqk_t, QKb, Wvo_t, VWt);
    // 4. e = exp(Q @ K^T / 16) bf16 (g2 v4 BN=256 MODE 8, 256 blocks, per batch)
    g2k<256, 8, 2><<<dim3(256), blk5, 0, stream>>>(
        QKb, (long)2048 * 512, 512, QKb + 256, (long)2048 * 512, 512,
        attnb, (long)2048 * 2048, 2048,
        256, 0.0625f, (const float*)nullptr, (const u16*)nullptr, 0L, 0,
        (const float*)nullptr, 0L, 8, 64);
    // 5. softmax2: row sums of e -> attn_f (fp32 output, NT stores) + inv_sum
    softmax2_kernel<<<dim3(8192), blk, 0, stream>>>(attnb, attn_f, inv_sum);
    // 6. residual(bf16) = bf16((e @ VW)*inv_sum + bo + Xb)
    //    (g2 v4 BN=128 MODE 9, 3-buffer counted pipeline, 256 blocks)
    g2k<128, 9, 3><<<dim3(256), blk5, 0, stream>>>(
        attnb, (long)2048 * 2048, 2048, VWt, 2048L, 8192,
        res_b, (long)2048 * 1024, 1024,
        2048, 1.0f, bo, Xb, (long)2048 * 1024, 1024,
        inv_sum, 2048L, 8, 64);
    // 7. h = relu(residual @ w1 + b1) (m97)
    gemm_bt<3><<<dim3(128), blk, 0, stream>>>(
        res_b, 0L, 1024, W1_t, 0L, 1024, hb, 0L, 256,
        (float*)nullptr, 0L, 0, 1024, 1.0f, b1, (const u16*)nullptr, 0L, 0, 2, 64);
    // 8. out = residual + h @ w2 + b2 (m97, fp32 NT stores)
    gemm_bt<7><<<dim3(512), blk, 0, stream>>>(
        hb, 0L, 256, W2_t, 0L, 256, (u16*)nullptr, 0L, 0,
        out_f, 0L, 1024, 256, 1.0f, b2, res_b, 0L, 1024, 8, 64);
}

// Round 15
// 180.137 us; speedup vs baseline: 1.0376x; 1.0289x over previous
//
#include <hip/hip_runtime.h>

typedef unsigned short u16;
typedef unsigned int u32;
typedef __bf16 bf16x8 __attribute__((ext_vector_type(8)));
typedef float f32x4 __attribute__((ext_vector_type(4)));

#define MTOT 8192
#define DM 1024
#define DI 256
#define TT 2048

#define AS1 __attribute__((address_space(1)))
#define AS3 __attribute__((address_space(3)))

__device__ __forceinline__ u16 f2bf(float f) {
    u32 u = __float_as_uint(f);
    return (u16)((u + 0x7fffu + ((u >> 16) & 1u)) >> 16);
}
__device__ __forceinline__ float b2f(u16 b) {
    return __uint_as_float((u32)b << 16);
}

// XCD-chunked bijective swizzle (all swizzled grids are %8==0).
__device__ __forceinline__ int xcd_swizzle(int bid, int nb) {
    return (bid & 7) * (nb >> 3) + (bid >> 3);
}

// ============ prep: X cvt + wv cvt + 5 weight transposes in ONE launch ============
__device__ __forceinline__ void transpose_tile(const float* __restrict__ in,
                                               u16* __restrict__ out, int K, int N,
                                               int bx, int by) {
    __shared__ float t[32][33];
    int n0 = bx * 32, k0 = by * 32;
    int tx = threadIdx.x & 31, ty = threadIdx.x >> 5;
    #pragma unroll
    for (int i = ty; i < 32; i += 8) t[i][tx] = in[(long)(k0 + i) * N + n0 + tx];
    __syncthreads();
    #pragma unroll
    for (int i = ty; i < 32; i += 8) out[(long)(n0 + i) * K + k0 + tx] = f2bf(t[tx][i]);
}

__device__ __forceinline__ void cvt_range(const float* __restrict__ in,
                                          u16* __restrict__ out, long n4, int b, int nb) {
    long i = (long)b * 256 + threadIdx.x;
    long stride = (long)nb * 256;
    for (; i < n4; i += stride) {
        float4 v = reinterpret_cast<const float4*>(in)[i];
        union { u16 u[4]; uint2 p; } o;
        o.u[0] = f2bf(v.x); o.u[1] = f2bf(v.y); o.u[2] = f2bf(v.z); o.u[3] = f2bf(v.w);
        reinterpret_cast<uint2*>(out)[i] = o.p;
    }
}

__global__ __launch_bounds__(256) void prep_kernel(
    const float* __restrict__ x, u16* __restrict__ Xb,
    const float* __restrict__ wq, const float* __restrict__ wk, u16* __restrict__ Wqk_t,
    const float* __restrict__ wv, u16* __restrict__ Wv_b,
    const float* __restrict__ wo, u16* __restrict__ Wo_t,
    const float* __restrict__ w1, u16* __restrict__ W1_t,
    const float* __restrict__ w2, u16* __restrict__ W2_t)
{
    int b = blockIdx.x;
    if (b < 1024) { cvt_range(x, Xb, (long)MTOT * DM / 4, b, 1024); return; }
    b -= 1024;
    if (b < 256)  { transpose_tile(wq, Wqk_t,              1024,  256, b & 7,  b >> 3); return; }
    b -= 256;
    if (b < 256)  { transpose_tile(wk, Wqk_t + 256 * 1024, 1024,  256, b & 7,  b >> 3); return; }
    b -= 256;
    if (b < 256)  { cvt_range(wv, Wv_b, (long)DM * DM / 4, b, 256); return; }
    b -= 256;
    if (b < 1024) { transpose_tile(wo, Wo_t,               1024, 1024, b & 31, b >> 5); return; }
    b -= 1024;
    if (b < 256)  { transpose_tile(w1, W1_t,               1024,  256, b & 7,  b >> 3); return; }
    b -= 256;
    transpose_tile(w2, W2_t, 256, 1024, b & 31, b >> 5);
}

// ------- softmax2: E holds e = exp(s) bf16 (unnormalized). Per row: sum e (fp32),
// write attn_f = e*inv (the fp32 output) and inv_sum[row]. -------
__global__ __launch_bounds__(256) void softmax2_kernel(const u16* __restrict__ E,
                                                       float* __restrict__ attn,
                                                       float* __restrict__ inv_sum) {
    long row = blockIdx.x;
    int tid = threadIdx.x;
    uint4 q = reinterpret_cast<const uint4*>(E + row * (long)TT)[tid];
    u32 w4[4] = {q.x, q.y, q.z, q.w};
    float vv[8];
    #pragma unroll
    for (int j = 0; j < 4; ++j) {
        vv[2 * j]     = __uint_as_float(w4[j] << 16);
        vv[2 * j + 1] = __uint_as_float(w4[j] & 0xffff0000u);
    }
    float s = 0.f;
    #pragma unroll
    for (int j = 0; j < 8; ++j) s += vv[j];
    #pragma unroll
    for (int off = 32; off; off >>= 1) s += __shfl_xor(s, off);
    __shared__ float reds[4];
    if ((tid & 63) == 0) reds[tid >> 6] = s;
    __syncthreads();
    s = reds[0] + reds[1] + reds[2] + reds[3];
    float inv = 1.0f / s;
    float* p = attn + row * (long)TT;
    reinterpret_cast<float4*>(p)[tid * 2] =
        make_float4(vv[0] * inv, vv[1] * inv, vv[2] * inv, vv[3] * inv);
    reinterpret_cast<float4*>(p)[tid * 2 + 1] =
        make_float4(vv[4] * inv, vv[5] * inv, vv[6] * inv, vv[7] * inv);
    if (tid == 0) inv_sum[row] = inv;
}

// ================== m97-structure 128x128 GEMM (Wvo + FFN) ==================
// MODE: 0 = bf16 C   3 = bf16 relu(C+bias)   7 = fp32(C+bias+addend_b)
template<int MODE>
__global__ __launch_bounds__(256) void gemm_bt(
    const u16* __restrict__ A, long sA, int lda,
    const u16* __restrict__ Bt, long sB, int ldb,
    u16* __restrict__ Cb, long sCb, int ldcb,
    float* __restrict__ Cf, long sCf, int ldcf,
    int K, float scale,
    const float* __restrict__ bias,
    const u16* __restrict__ addend_b, long sAdd, int ld_add,
    int gx, int gy)
{
    __shared__ __attribute__((aligned(16))) u16 As[128 * 64];
    __shared__ __attribute__((aligned(16))) u16 Bs[128 * 64];

    int lid = xcd_swizzle(blockIdx.x, gridDim.x);
    int x = lid % gx;
    int t = lid / gx;
    int y = t % gy;
    int z = t / gy;
    long tile_m = (long)y * 128, tile_n = (long)x * 128;
    const u16* Az = A + (long)z * sA;
    const u16* Btz = Bt + (long)z * sB;

    const int tid = threadIdx.x;
    const int w = tid >> 6;
    const int l = tid & 63;
    const int lane15 = l & 15;
    const int lhi = l >> 4;

    const int srow = w * 8 + (l >> 3);
    const int scol = (((l & 7) ^ (l >> 3)) << 4) >> 1;

    const u16* aptr = Az + (tile_m + srow) * (long)lda + scol;
    const u16* bptr = Btz + (tile_n + srow) * (long)ldb + scol;

    f32x4 acc[4][4] = {};

    const int wr = (w >> 1) * 64;
    const int wc = (w & 1) * 64;

    for (int k0 = 0; k0 < K; k0 += 64) {
        #pragma unroll
        for (int i = 0; i < 4; ++i) {
            __builtin_amdgcn_global_load_lds(
                (const AS1 void*)(aptr + (long)i * 32 * lda + k0),
                (AS3 void*)((char*)As + i * 4096 + w * 1024), 16, 0, 0);
        }
        #pragma unroll
        for (int i = 0; i < 4; ++i) {
            __builtin_amdgcn_global_load_lds(
                (const AS1 void*)(bptr + (long)i * 32 * ldb + k0),
                (AS3 void*)((char*)Bs + i * 4096 + w * 1024), 16, 0, 0);
        }
        __syncthreads();
        #pragma unroll
        for (int kk = 0; kk < 2; ++kk) {
            bf16x8 af[4], bfr[4];
            const int kb = (kk * 32 + lhi * 8) * 2;
            #pragma unroll
            for (int m = 0; m < 4; ++m) {
                int r = wr + m * 16 + lane15;
                af[m] = *reinterpret_cast<const bf16x8*>(
                    (const char*)As + r * 128 + (kb ^ ((r & 7) << 4)));
            }
            #pragma unroll
            for (int n = 0; n < 4; ++n) {
                int r = wc + n * 16 + lane15;
                bfr[n] = *reinterpret_cast<const bf16x8*>(
                    (const char*)Bs + r * 128 + (kb ^ ((r & 7) << 4)));
            }
            #pragma unroll
            for (int m = 0; m < 4; ++m)
                #pragma unroll
                for (int n = 0; n < 4; ++n)
                    acc[m][n] = __builtin_amdgcn_mfma_f32_16x16x32_bf16(
                        af[m], bfr[n], acc[m][n], 0, 0, 0);
        }
        __syncthreads();
    }

    float* Cfz = Cf + (long)z * sCf;
    u16* Cbz = Cb + (long)z * sCb;
    const u16* addz = addend_b ? addend_b + (long)z * sAdd : addend_b;
    #pragma unroll
    for (int m = 0; m < 4; ++m) {
        #pragma unroll
        for (int n = 0; n < 4; ++n) {
            long grow0 = tile_m + wr + m * 16 + lhi * 4;
            long gcol  = tile_n + wc + n * 16 + lane15;
            #pragma unroll
            for (int r = 0; r < 4; ++r) {
                long grow = grow0 + r;
                float v = acc[m][n][r];
                if (MODE == 3 || MODE == 7) v += bias[gcol];
                if (MODE == 7) v += b2f(addz[grow * (long)ld_add + gcol]);
                if (MODE == 3) v = fmaxf(v, 0.0f);
                if (MODE == 0 || MODE == 3) Cbz[grow * (long)ldcb + gcol] = f2bf(v);
                if (MODE == 7) Cfz[grow * (long)ldcf + gcol] = v;
            }
        }
    }
}

// ====== g2 v4: BM=256, BN=(256|128), BK=64, 8 waves, dedup'd ds_reads, NBUF buffers ======
// BN=256: waves 2M x 4N, wave tile 128x64, MF=8 (reads/MFMA = 0.375).
// BN=128: waves 4M x 2N, wave tile 64x64,  MF=4 (reads/MFMA = 0.5).
// NBUF=2: STAGE(t+1) at top of tile t, end-of-tile vmcnt(0) (covered by the tile).
// NBUF=3 (BN=128 only): STAGE(t+2) at top of tile t, end-of-tile vmcnt(6) keeps
// t+2's loads in flight -> STAGE(t+1) gets ~2 tiles of cover (T4).
// Raw s_barrier only. XOR-16B swizzle on staging source + ds_read (0 conflicts).
// MODE: 0 = bf16(C*scale)        8 = bf16(exp(C*scale))
//       9 = bf16(C*inv_sum[row] + bias[col] + bf16 addend)
template<int BN, int MODE, int NBUF>
__device__ __forceinline__ void g2_body(
    char* ldsb,
    const u16* __restrict__ A, int lda,
    const u16* __restrict__ Bt, int ldb,
    u16* __restrict__ Cb, int ldcb,
    int K, float scale,
    const float* __restrict__ bias,
    const u16* __restrict__ addend_b, int ld_add,
    const float* __restrict__ inv_sum,
    long tile_m, long tile_n)
{
    constexpr int WNM = (BN == 256) ? 2 : 4;   // waves along M
    constexpr int WNN = 8 / WNM;               // waves along N
    constexpr int MF  = 16 / WNM;              // m-frags per wave (8 or 4)
    constexpr int WTM = 256 / WNM;             // wave tile rows (128 or 64)
    constexpr int BUFB = (256 + BN) * 128;     // bytes per K-tile buffer
    constexpr int AC = 4;                      // A stage chunks (64 rows each)
    constexpr int BC = BN / 64;                // B stage chunks

    const int tid = threadIdx.x;
    const int w = tid >> 6, l = tid & 63;
    const int lane15 = l & 15, lhi = l >> 4;
    const int sw = (l & 7) << 4;
    const int wm = w / WNN, wn = w % WNN;

    const int srow = w * 8 + (l >> 3);
    const int scol = ((l & 7) ^ (l >> 3)) * 8;
    const u16* aS = A + (tile_m + srow) * (long)lda + scol;
    const u16* bS = Bt + (tile_n + srow) * (long)ldb + scol;

    auto STAGE = [&](int t) {
        const long kof = (long)t << 6;
        char* buf = ldsb + (size_t)(t % NBUF) * BUFB;
        #pragma unroll
        for (int c = 0; c < AC; ++c)
            __builtin_amdgcn_global_load_lds(
                (const AS1 void*)(aS + (long)(c * 64) * lda + kof),
                (AS3 void*)(buf + c * 8192 + w * 1024), 16, 0, 0);
        #pragma unroll
        for (int c = 0; c < BC; ++c)
            __builtin_amdgcn_global_load_lds(
                (const AS1 void*)(bS + (long)(c * 64) * ldb + kof),
                (AS3 void*)(buf + 32768 + c * 8192 + w * 1024), 16, 0, 0);
    };

    f32x4 acc[MF][4] = {};
    const int NT = K >> 6;

    if (NBUF == 3) {
        STAGE(0); STAGE(1);
        asm volatile("s_waitcnt vmcnt(6)" ::: "memory");   // AC+BC=6 (BN=128): tile1 in flight
    } else {
        STAGE(0);
        asm volatile("s_waitcnt vmcnt(0)" ::: "memory");
    }
    __builtin_amdgcn_s_barrier();

    for (int t = 0; t < NT; ++t) {
        const char* ab = ldsb + (size_t)(t % NBUF) * BUFB;
        const char* bb = ab + 32768;
        const bool more = (t + 1) < NT;
        const bool st2 = (t + 2) < NT;

        if (NBUF == 3) { if (st2) STAGE(t + 2); }
        else           { if (more) STAGE(t + 1); }

        // B fragments: read once per K-tile
        bf16x8 bfr[4][2];
        #pragma unroll
        for (int n = 0; n < 4; ++n) {
            const int rb = wn * 64 + n * 16 + lane15;
            #pragma unroll
            for (int ks = 0; ks < 2; ++ks)
                bfr[n][ks] = *reinterpret_cast<const bf16x8*>(
                    bb + rb * 128 + ((ks * 64 + lhi * 16) ^ sw));
        }
        // A in halves of 4 m-frags; each half: 8 reads -> 32 MFMA
        #pragma unroll
        for (int h = 0; h < MF / 4; ++h) {
            bf16x8 af[4][2];
            #pragma unroll
            for (int m = 0; m < 4; ++m) {
                const int r = wm * WTM + h * 64 + m * 16 + lane15;
                #pragma unroll
                for (int ks = 0; ks < 2; ++ks)
                    af[m][ks] = *reinterpret_cast<const bf16x8*>(
                        ab + r * 128 + ((ks * 64 + lhi * 16) ^ sw));
            }
            __builtin_amdgcn_s_barrier();
            __builtin_amdgcn_s_setprio(1);
            #pragma unroll
            for (int m = 0; m < 4; ++m)
                #pragma unroll
                for (int n = 0; n < 4; ++n)
                    #pragma unroll
                    for (int ks = 0; ks < 2; ++ks)
                        acc[h * 4 + m][n] = __builtin_amdgcn_mfma_f32_16x16x32_bf16(
                            af[m][ks], bfr[n][ks], acc[h * 4 + m][n], 0, 0, 0);
            __builtin_amdgcn_s_setprio(0);
        }
        if (NBUF == 3) {
            if (more) {
                if (st2) asm volatile("s_waitcnt vmcnt(6)" ::: "memory");
                else     asm volatile("s_waitcnt vmcnt(0)" ::: "memory");
            }
        } else {
            if (more) asm volatile("s_waitcnt vmcnt(0)" ::: "memory");
        }
        __builtin_amdgcn_s_barrier();
    }

    #pragma unroll
    for (int mf = 0; mf < MF; ++mf) {
        #pragma unroll
        for (int nf = 0; nf < 4; ++nf) {
            const long grow0 = tile_m + wm * WTM + mf * 16 + lhi * 4;
            const long gcol  = tile_n + wn * 64 + nf * 16 + lane15;
            #pragma unroll
            for (int r = 0; r < 4; ++r) {
                const long grow = grow0 + r;
                float v = acc[mf][nf][r];
                if (MODE == 0) v *= scale;
                if (MODE == 8) v = __expf(v * scale);
                if (MODE == 9) v = v * inv_sum[grow] + bias[gcol]
                                   + b2f(addend_b[grow * (long)ld_add + gcol]);
                Cb[grow * (long)ldcb + gcol] = f2bf(v);
            }
        }
    }
}

template<int BN, int MODE, int NBUF>
__global__ __launch_bounds__(512) void g2k(
    const u16* __restrict__ A, long sA, int lda,
    const u16* __restrict__ Bt, long sB, int ldb,
    u16* __restrict__ Cb, long sCb, int ldcb,
    int K, float scale,
    const float* __restrict__ bias,
    const u16* __restrict__ addend_b, long sAdd, int ld_add,
    const float* __restrict__ inv_sum, long sInv,
    int gx, int tpz)
{
    __shared__ __attribute__((aligned(16))) char lds[(256 + BN) * 128 * NBUF];
    int lid = xcd_swizzle(blockIdx.x, gridDim.x);
    int z = lid / tpz, rem = lid % tpz;
    int x = rem % gx, y = rem / gx;
    g2_body<BN, MODE, NBUF>(lds,
                      A + (long)z * sA, lda, Bt + (long)z * sB, ldb,
                      Cb + (long)z * sCb, ldcb, K, scale, bias,
                      addend_b ? addend_b + (long)z * sAdd : addend_b, ld_add,
                      inv_sum ? inv_sum + (long)z * sInv : inv_sum,
                      (long)y * 256, (long)x * BN);
}

// Merged QK + VW^T dispatch (K=1024 both) — r11 geometry (measured best):
// lids [0,64):   QK = Xb @ Wqk_t^T (8192x512): BN=256, x = lid&1, y = lid>>1
// lids [64,192): VW^T = Wvo_t @ Xb^T -> VWt (1024,8192) row-major, y-fast
//   (y = l2&3, x = l2>>2): per-XCD = full Wvo_t (2MB) + 4 X panels (2MB) ~= L2.
__global__ __launch_bounds__(512) void g2_qkvw(
    const u16* __restrict__ Xb, const u16* __restrict__ Wqk_t, u16* __restrict__ QKb,
    const u16* __restrict__ Wvo_t, u16* __restrict__ VWt)
{
    __shared__ __attribute__((aligned(16))) char lds[131072];
    int lid = xcd_swizzle(blockIdx.x, gridDim.x);
    if (lid < 64) {
        int x = lid & 1, y = lid >> 1;
        g2_body<256, 0, 2>(lds, Xb, 1024, Wqk_t, 1024, QKb, 512,
                        1024, 1.0f, (const float*)nullptr, (const u16*)nullptr, 0,
                        (const float*)nullptr, (long)y * 256, (long)x * 256);
    } else {
        int l2 = lid - 64;
        int y = l2 & 3, x = l2 >> 2;
        g2_body<256, 0, 2>(lds, Wvo_t, 1024, Xb, 1024, VWt, 8192,
                        1024, 1.0f, (const float*)nullptr, (const u16*)nullptr, 0,
                        (const float*)nullptr, (long)y * 256, (long)x * 256);
    }
}

extern "C" void kernel_launch(void* const* d_in, const int* in_sizes, int n_in,
                              void* d_out, int out_size, void* d_ws, size_t ws_size,
                              hipStream_t stream)
{
    const float* x  = (const float*)d_in[0];
    const float* wq = (const float*)d_in[1];
    const float* wk = (const float*)d_in[2];
    const float* wv = (const float*)d_in[3];
    const float* wo = (const float*)d_in[4];
    const float* bo = (const float*)d_in[5];
    const float* w1 = (const float*)d_in[6];
    const float* b1 = (const float*)d_in[7];
    const float* w2 = (const float*)d_in[8];
    const float* b2 = (const float*)d_in[9];

    float* out_f  = (float*)d_out;
    float* attn_f = out_f + (long)MTOT * DM;

    char* ws = (char*)d_ws;
    u16* Xb    = (u16*)(ws + 0);            // 16 MB bf16 X (also residual addend)
    u16* Wqk_t = (u16*)(ws + 16777216);     // 1 MB  (512,1024)
    u16* Wv_b  = (u16*)(ws + 17825792);     // 2 MB  wv bf16 (as-is, K-contig)
    u16* Wo_t  = (u16*)(ws + 19922944);     // 2 MB  wo^T
    u16* W1_t  = (u16*)(ws + 22020096);     // 0.5 MB
    u16* W2_t  = (u16*)(ws + 22544384);     // 0.5 MB
    u16* Wvo_t = (u16*)(ws + 23068672);     // 2 MB  (Wv@Wo)^T
    u16* QKb   = (u16*)(ws + 25165824);     // 8 MB  (8192,512) (reused as h)
    u16* VWt   = (u16*)(ws + 33554432);     // 16 MB (1024,8192)
    u16* attnb = (u16*)(ws + 50331648);     // 32 MB e = exp(scores) bf16 (unnormalized)
    u16* res_b = (u16*)(ws + 83886080);     // 16 MB residual bf16
    float* inv_sum = (float*)(ws + 100663296); // 32 KB per-row 1/sum
    u16* hb    = QKb;

    dim3 blk(256), blk5(512);

    // 1. prep: X cvt, wv cvt, wq/wk/wo/w1/w2 transposes
    prep_kernel<<<dim3(3328), blk, 0, stream>>>(x, Xb, wq, wk, Wqk_t, wv, Wv_b,
                                                wo, Wo_t, w1, W1_t, w2, W2_t);
    // 2. Wvo^T = Wo_t @ Wv_b^T (m97 mode 0, coalesced stores)
    gemm_bt<0><<<dim3(64), blk, 0, stream>>>(
        Wo_t, 0L, 1024, Wv_b, 0L, 1024, Wvo_t, 0L, 1024,
        (float*)nullptr, 0L, 0, 1024, 1.0f, (const float*)nullptr,
        (const u16*)nullptr, 0L, 0, 8, 8);
    // 3. merged QK + VW^T (g2 v4, 192 blocks; VW via swapped operands, mode 0)
    g2_qkvw<<<dim3(192), blk5, 0, stream>>>(Xb, Wqk_t, QKb, Wvo_t, VWt);
    // 4. e = exp(Q @ K^T / 16) bf16 (g2 v4 BN=256 MODE 8, 256 blocks, per batch)
    g2k<256, 8, 2><<<dim3(256), blk5, 0, stream>>>(
        QKb, (long)2048 * 512, 512, QKb + 256, (long)2048 * 512, 512,
        attnb, (long)2048 * 2048, 2048,
        256, 0.0625f, (const float*)nullptr, (const u16*)nullptr, 0L, 0,
        (const float*)nullptr, 0L, 8, 64);
    // 5. softmax2: row sums of e -> attn_f (fp32 output) + inv_sum
    softmax2_kernel<<<dim3(8192), blk, 0, stream>>>(attnb, attn_f, inv_sum);
    // 6. residual(bf16) = bf16((e @ VW)*inv_sum + bo + Xb)
    //    (g2 v4 BN=128 MODE 9, 3-buffer counted pipeline, 256 blocks)
    g2k<128, 9, 3><<<dim3(256), blk5, 0, stream>>>(
        attnb, (long)2048 * 2048, 2048, VWt, 2048L, 8192,
        res_b, (long)2048 * 1024, 1024,
        2048, 1.0f, bo, Xb, (long)2048 * 1024, 1024,
        inv_sum, 2048L, 8, 64);
    // 7. h = relu(residual @ w1 + b1) (m97)
    gemm_bt<3><<<dim3(128), blk, 0, stream>>>(
        res_b, 0L, 1024, W1_t, 0L, 1024, hb, 0L, 256,
        (float*)nullptr, 0L, 0, 1024, 1.0f, b1, (const u16*)nullptr, 0L, 0, 2, 64);
    // 8. out = residual + h @ w2 + b2 (m97, fp32 out)
    gemm_bt<7><<<dim3(512), blk, 0, stream>>>(
        hb, 0L, 256, W2_t, 0L, 256, (u16*)nullptr, 0L, 0,
        out_f, 0L, 1024, 256, 1.0f, b2, res_b, 0L, 1024, 8, 64);
}